// Round 15
// baseline (210.062 us; speedup 1.0000x reference)
//
#include <hip/hip_runtime.h>
#include <math.h>

// GQA B=1 S=2048 D=128 H=32 KVH=8. d_out f32.
// Round 15: (a) separate MFMA Q-projection restored (r14's fused scalar Q-proj
// was ~30us of VALU + 1GB L2 traffic; FETCH evidence re-read: qproj reads are
// L3-hits, so ws>=27MB is likely and the big path ran in r11); (b) 512-thread
// blocks: 8 waves = 4 heads x 2 kv-groups -> 16 waves/CU (was 8) at 2 blocks/CU.
// Epilogue: per-head pair-sum of (O,l) via LDS, per-head O@Wo, 4-head LDS sum,
// plain stores to part[g] (no atomics). reduce_out sums 8 g + bias.

#define SCALE_L2E 0.12751878222550723f   // (1/sqrt(128)) * log2(e)
#define L2_10K_64 0.20762050593045952f   // log2(10000)/64

typedef short bf16x8 __attribute__((ext_vector_type(8)));
typedef float f32x4 __attribute__((ext_vector_type(4)));
typedef float f32x16 __attribute__((ext_vector_type(16)));

__device__ __forceinline__ unsigned short f2b(float f) {
  union { float f; unsigned u; } x; x.f = f;
  return (unsigned short)((x.u + 0x7FFFu + ((x.u >> 16) & 1u)) >> 16);
}
__device__ __forceinline__ float b2f(unsigned short b) {
  union { unsigned u; float f; } x; x.u = ((unsigned)b) << 16;
  return x.f;
}
__device__ __forceinline__ void lds_dma16(void* lds, const void* g) {
  __builtin_amdgcn_global_load_lds(
      (const __attribute__((address_space(1))) unsigned int*)g,
      (__attribute__((address_space(3))) unsigned int*)lds, 16, 0, 0);
}
__device__ __forceinline__ unsigned cvtpk(float lo, float hi) {
  unsigned r;
  asm("v_cvt_pk_bf16_f32 %0, %1, %2" : "=v"(r) : "v"(lo), "v"(hi));
  return r;
}
#define PLSWAP(a, b) asm("v_permlane32_swap_b32 %0, %1" : "+v"(a), "+v"(b))

__device__ __forceinline__ void redist(unsigned pw[8], bf16x8* f0, bf16x8* f1) {
  PLSWAP(pw[0], pw[2]); PLSWAP(pw[1], pw[3]);
  PLSWAP(pw[4], pw[6]); PLSWAP(pw[5], pw[7]);
  union { unsigned u[4]; bf16x8 v; } a, b;
  a.u[0] = pw[0]; a.u[1] = pw[1]; a.u[2] = pw[2]; a.u[3] = pw[3];
  b.u[0] = pw[4]; b.u[1] = pw[5]; b.u[2] = pw[6]; b.u[3] = pw[7];
  *f0 = a.v; *f1 = b.v;
}

// ---- weight prep: LDS 64x64 tile transposes; Wq transpose (big) or cast ----
__global__ __launch_bounds__(256) void prep_weights(
    const float* __restrict__ Wk, const float* __restrict__ Wv,
    const float* __restrict__ Wo, const float* __restrict__ Wq,
    unsigned short* __restrict__ Wkt, unsigned short* __restrict__ Wvt,
    unsigned short* __restrict__ Wot, unsigned short* __restrict__ Wq2, int big) {
  __shared__ unsigned short T[64][66];
  int b = blockIdx.x, tid = threadIdx.x;
  const float* W;
  unsigned short* D;
  int K, N, tk, tn;
  if (b < 32) {
    W = Wk; D = Wkt; K = 128; N = 1024; int ti = b;       tk = ti & 1;  tn = ti >> 1;
  } else if (b < 64) {
    W = Wv; D = Wvt; K = 128; N = 1024; int ti = b - 32;  tk = ti & 1;  tn = ti >> 1;
  } else if (b < 192) {
    W = Wo; D = Wot; K = 4096; N = 128; int ti = b - 64;  tk = ti >> 1; tn = ti & 1;
  } else {
    if (!big) {
      int i0 = ((b - 192) * 256 + tid) * 16;  // Wq cast row-major bf16
#pragma unroll
      for (int j = 0; j < 16; ++j) Wq2[i0 + j] = f2b(Wq[i0 + j]);
      return;
    }
    W = Wq; D = Wq2; K = 128; N = 4096; int ti = b - 192; tk = ti & 1;  tn = ti >> 1;
  }
  int k0 = tk * 64, n0 = tn * 64;
  int c = tid & 63, q = tid >> 6;
#pragma unroll
  for (int i = 0; i < 16; ++i) {
    int r = i * 4 + q;
    T[r][c] = f2b(W[(size_t)(k0 + r) * N + n0 + c]);
  }
  __syncthreads();
#pragma unroll
  for (int i = 0; i < 16; ++i) {
    int r = i * 4 + q;
    D[(size_t)(n0 + r) * K + k0 + c] = T[c][r];
  }
}

// ---- K+V projections with fused RoPE (verified since r10) ----
__global__ __launch_bounds__(256) void proj_kv(
    const float* __restrict__ keys, const float* __restrict__ values,
    const unsigned short* __restrict__ Wkt, const unsigned short* __restrict__ Wvt,
    const float* __restrict__ bk, const float* __restrict__ bv,
    unsigned short* __restrict__ kp, unsigned short* __restrict__ vt) {
  int bx = blockIdx.x, m0 = blockIdx.y * 64;
  int tid = threadIdx.x;
  int w = tid >> 6, l = tid & 63;
  int l16 = l & 15, g4 = l >> 4;
  int arow = m0 + w * 16 + l16;
  const f32x4 fz = {0.f, 0.f, 0.f, 0.f};
  int vmode = bx >> 3;
  int n0 = (bx & 7) * 128, tb = bx & 7;
  const float* X = vmode ? values : keys;
  const unsigned short* Wt = vmode ? Wvt : Wkt;
  const float* bias = vmode ? bv : bk;
  f32x4 acc[8];
#pragma unroll
  for (int nb = 0; nb < 8; ++nb) acc[nb] = fz;
#pragma unroll
  for (int kc = 0; kc < 4; ++kc) {
    int kbase = kc * 32 + g4 * 8;
    const float* xp = X + (size_t)arow * 128 + kbase;
    bf16x8 a;
#pragma unroll
    for (int j = 0; j < 8; ++j) a[j] = (short)f2b(xp[j]);
#pragma unroll
    for (int nb = 0; nb < 8; ++nb) {
      bf16x8 b = *(const bf16x8*)(Wt + (size_t)(n0 + nb * 16 + l16) * 128 + kbase);
      acc[nb] = __builtin_amdgcn_mfma_f32_16x16x32_bf16(a, b, acc[nb], 0, 0, 0);
    }
  }
#pragma unroll
  for (int nb = 0; nb < 4; ++nb) {
    int d2 = nb * 16 + l16;
    float invf = exp2f(-(float)d2 * L2_10K_64);
    float blo = bias[n0 + d2], bhi = bias[n0 + d2 + 64];
#pragma unroll
    for (int r = 0; r < 4; ++r) {
      int mi = m0 + w * 16 + g4 * 4 + r;
      int t = (mi & 255) * 8 + tb;
      float ang = (float)t * invf;
      float sf, cf;
      __sincosf(ang, &sf, &cf);
      float x1 = acc[nb][r] + blo;
      float x2 = acc[nb + 4][r] + bhi;
      unsigned short lo = f2b(x1 * cf - x2 * sf);
      unsigned short hi = f2b(x2 * cf + x1 * sf);
      int g = mi >> 8;
      if (vmode) {
        vt[(size_t)g * 262144 + (size_t)d2 * 2048 + t] = lo;
        vt[(size_t)g * 262144 + (size_t)(d2 + 64) * 2048 + t] = hi;
      } else {
        kp[(size_t)g * 262144 + (size_t)t * 128 + d2] = lo;
        kp[(size_t)g * 262144 + (size_t)t * 128 + d2 + 64] = hi;
      }
    }
  }
}

// ---- Q projection (big path): qp de-scrambled (H,S,D) ----
//   C[mi][n] == q[h=mi>>6][s=((mi&63)<<5)|(n>>7)][d=n&127]
__global__ __launch_bounds__(256) void proj_q(const float* __restrict__ X,
                                              const unsigned short* __restrict__ Wqt,
                                              const float* __restrict__ bq,
                                              unsigned short* __restrict__ qp) {
  int n0 = blockIdx.x * 64, m0 = blockIdx.y * 64;
  int tid = threadIdx.x;
  int w = tid >> 6, l = tid & 63;
  int l16 = l & 15, g4 = l >> 4;
  int arow = m0 + w * 16 + l16;
  const f32x4 fz = {0.f, 0.f, 0.f, 0.f};
  f32x4 acc[4];
#pragma unroll
  for (int nb = 0; nb < 4; ++nb) acc[nb] = fz;
#pragma unroll
  for (int kc = 0; kc < 4; ++kc) {
    int kbase = kc * 32 + g4 * 8;
    const float* xp = X + (size_t)arow * 128 + kbase;
    bf16x8 a;
#pragma unroll
    for (int j = 0; j < 8; ++j) a[j] = (short)f2b(xp[j]);
#pragma unroll
    for (int nb = 0; nb < 4; ++nb) {
      bf16x8 b = *(const bf16x8*)(Wqt + (size_t)(n0 + nb * 16 + l16) * 128 + kbase);
      acc[nb] = __builtin_amdgcn_mfma_f32_16x16x32_bf16(a, b, acc[nb], 0, 0, 0);
    }
  }
#pragma unroll
  for (int nb = 0; nb < 4; ++nb) {
    int n = n0 + nb * 16 + l16;
    float bvv = bq[n];
#pragma unroll
    for (int r = 0; r < 4; ++r) {
      int mi = m0 + w * 16 + g4 * 4 + r;
      int h = mi >> 6;
      int s = ((mi & 63) << 5) | (n >> 7);
      qp[((size_t)h * 2048 + s) * 128 + (n & 127)] = f2b(acc[nb][r] + bvv);
    }
  }
}

__global__ void ws_marker(float* __restrict__ out) {
  out[blockIdx.x * 256 + threadIdx.x] = 12345.0f;
}

__global__ void reduce_out(const float* __restrict__ part, const float* __restrict__ bo,
                           float* __restrict__ out) {
  int idx = blockIdx.x * 256 + threadIdx.x;
  float s = bo[idx & 127];
#pragma unroll
  for (int g = 0; g < 8; ++g) s += part[(size_t)g * 262144 + idx];
  out[idx] = s;
}

// Grid 512 x 512thr: g=bid&7, q-tile(32)=bid>>3. 8 waves = 4 heads x 2 kv-groups.
// LDS: K[2][64][128]sh @0 (32KB, 4-bit XOR) | V^T[2][128][64]sh @32768 (32KB,
// 3-bit XOR). Epilogue reuses smem as 4 x [128][33] f32 head-slabs + Laux.
template <int FUSED_Q>
__global__ __launch_bounds__(512, 4) void attn_kernel(
    const float* __restrict__ X, const unsigned short* __restrict__ Wqb,
    const float* __restrict__ bq, const unsigned short* __restrict__ qp,
    const unsigned short* __restrict__ kp, const unsigned short* __restrict__ vt,
    const unsigned short* __restrict__ Wot, float* __restrict__ part) {
  __shared__ __align__(16) char smem[69632];
  int bid = blockIdx.x;
  int g = bid & 7;
  int qi0 = (bid >> 3) * 32;
  int q5 = qi0 >> 5;
  int tid = threadIdx.x;
  int w = tid >> 6, l = tid & 63;
  int l31 = l & 31, hi = l >> 5;
  int hh = w >> 1, jb = w & 1;
  int hw = g + 8 * hh;  // this wave's head

  const f32x16 fz16 = {0.f};
  bf16x8 qfrag[8];

  if (FUSED_Q) {
    // fallback: 4 rows of X@Wq (heads {g+8j} at C-row q5), 512 threads x 8 cols
    unsigned short* Uni = (unsigned short*)smem;  // [4][4096]
    int col0 = tid * 8;
    {
      float acc[4][8];
#pragma unroll
      for (int jj = 0; jj < 4; ++jj)
#pragma unroll
        for (int e = 0; e < 8; ++e) acc[jj][e] = bq[col0 + e];
      const float* xr0 = X + (size_t)((g + 0) * 64 + q5) * 128;
      const float* xr1 = X + (size_t)((g + 8) * 64 + q5) * 128;
      const float* xr2 = X + (size_t)((g + 16) * 64 + q5) * 128;
      const float* xr3 = X + (size_t)((g + 24) * 64 + q5) * 128;
      for (int k = 0; k < 128; ++k) {
        float x0 = xr0[k], x1 = xr1[k], x2 = xr2[k], x3 = xr3[k];
        bf16x8 w0 = *(const bf16x8*)(Wqb + (size_t)k * 4096 + col0);
#pragma unroll
        for (int e = 0; e < 8; ++e) {
          float f0 = b2f((unsigned short)w0[e]);
          acc[0][e] += x0 * f0; acc[1][e] += x1 * f0;
          acc[2][e] += x2 * f0; acc[3][e] += x3 * f0;
        }
      }
#pragma unroll
      for (int jj = 0; jj < 4; ++jj)
#pragma unroll
        for (int e = 0; e < 8; ++e) Uni[jj * 4096 + col0 + e] = f2b(acc[jj][e]);
    }
    __syncthreads();
#pragma unroll
    for (int kc = 0; kc < 8; ++kc)
      qfrag[kc] = *(const bf16x8*)&Uni[hh * 4096 + l31 * 128 + kc * 16 + hi * 8];
    __syncthreads();  // Uni reads done before DMA overwrites region
  } else {
    const unsigned short* qrow = qp + ((size_t)hw * 2048 + qi0 + l31) * 128;
#pragma unroll
    for (int kc = 0; kc < 8; ++kc)
      qfrag[kc] = *(const bf16x8*)(qrow + kc * 16 + hi * 8);
  }

  const char* kg = (const char*)(kp + (size_t)g * 262144);
  const char* vg = (const char*)(vt + (size_t)g * 262144);

  // waves 0-3 stage K (16KB), waves 4-7 stage V (16KB); 4 DMA instrs each
#define STAGE(tn, cb)                                                           \
  {                                                                             \
    int w4 = w & 3;                                                             \
    if (w < 4) {                                                                \
      _Pragma("unroll") for (int i = 0; i < 4; ++i) {                           \
        int off = w4 * 4096 + i * 1024 + l * 16;                                \
        int row = off >> 8, ch = (off >> 4) & 15;                               \
        int rch = ch ^ (row & 15);                                              \
        lds_dma16(smem + (cb) * 16384 + w4 * 4096 + i * 1024,                   \
                  kg + (size_t)(tn) * 16384 + (size_t)row * 256 + rch * 16);    \
      }                                                                         \
    } else {                                                                    \
      _Pragma("unroll") for (int i = 0; i < 4; ++i) {                           \
        int off = w4 * 4096 + i * 1024 + l * 16;                                \
        int row = off >> 7, ch = (off >> 4) & 7;                                \
        int rch = ch ^ (row & 7);                                               \
        lds_dma16(smem + 32768 + (cb) * 16384 + w4 * 4096 + i * 1024,           \
                  vg + (size_t)row * 4096 + (size_t)(tn) * 128 + rch * 16);     \
      }                                                                         \
    }                                                                           \
  }

  STAGE(0, 0);
  __syncthreads();

  f32x16 oacc[4];  // O^T[d][q=l31], partial over this wave's kv-groups
#pragma unroll
  for (int db = 0; db < 4; ++db) oacc[db] = fz16;
  float lacc = 0.f;

  int c = 0;
  for (int t = 0; t < 32; ++t) {
    if (t < 31) STAGE(t + 1, c ^ 1);

    f32x16 sacc = fz16;
    __builtin_amdgcn_s_setprio(1);
#pragma unroll
    for (int kc = 0; kc < 8; ++kc) {
      int row = jb * 32 + l31;
      int rch = (kc * 2 + hi) ^ (row & 15);
      bf16x8 kfrag = *(const bf16x8*)(smem + c * 16384 + row * 256 + rch * 16);
      sacc = __builtin_amdgcn_mfma_f32_32x32x16_bf16(kfrag, qfrag[kc], sacc, 0, 0, 0);
    }
    __builtin_amdgcn_s_setprio(0);
    float p[16];
#pragma unroll
    for (int j = 0; j < 16; ++j) {
      p[j] = exp2f(sacc[j] * SCALE_L2E);
      lacc += p[j];
    }
    unsigned pw[8];
#pragma unroll
    for (int m = 0; m < 8; ++m) pw[m] = cvtpk(p[2 * m], p[2 * m + 1]);
    bf16x8 pf0, pf1;
    redist(pw, &pf0, &pf1);
    __builtin_amdgcn_s_setprio(1);
#pragma unroll
    for (int ks = 0; ks < 2; ++ks) {
      int ksg = jb * 2 + ks;
      bf16x8 pf = ks ? pf1 : pf0;
#pragma unroll
      for (int db = 0; db < 4; ++db) {
        int row = db * 32 + l31;
        int rch = (ksg * 2 + hi) ^ (row & 7);
        bf16x8 vfrag = *(const bf16x8*)(smem + 32768 + c * 16384 + row * 128 + rch * 16);
        oacc[db] = __builtin_amdgcn_mfma_f32_32x32x16_bf16(vfrag, pf, oacc[db], 0, 0, 0);
      }
    }
    __builtin_amdgcn_s_setprio(0);
    __syncthreads();
    c ^= 1;
  }

  // lane's lacc covers its hi-half of this wave's 32-kv groups; xor-32 first
  float lw = lacc + __shfl_xor(lacc, 32, 64);

  // ---- epilogue ----
  float* smemF = (float*)smem;
  float* Ph = smemF + hh * 4224;           // per-head slab [128][33] f32
  float* Laux = smemF + 4 * 4224;          // 8 floats
  if (jb == 0) {
#pragma unroll
    for (int db = 0; db < 4; ++db)
#pragma unroll
      for (int j = 0; j < 16; ++j) {
        int d = db * 32 + (j & 3) + 8 * (j >> 2) + 4 * hi;
        Ph[d * 33 + l31] = oacc[db][j];
      }
    if (l == 0) Laux[w] = lw;
  }
  __syncthreads();
  if (jb == 1) {
    float invl = 1.f / (lw + Laux[w - 1]);
    bf16x8 ofrag[8];
#pragma unroll
    for (int db = 0; db < 4; ++db) {
      float ov[16];
#pragma unroll
      for (int j = 0; j < 16; ++j) {
        int d = db * 32 + (j & 3) + 8 * (j >> 2) + 4 * hi;
        ov[j] = (Ph[d * 33 + l31] + oacc[db][j]) * invl;
      }
      unsigned pw[8];
#pragma unroll
      for (int m = 0; m < 8; ++m) pw[m] = cvtpk(ov[2 * m], ov[2 * m + 1]);
      redist(pw, &ofrag[db * 2], &ofrag[db * 2 + 1]);
    }
    f32x16 acc2[4];
#pragma unroll
    for (int nb = 0; nb < 4; ++nb) acc2[nb] = fz16;
#pragma unroll
    for (int ks = 0; ks < 8; ++ks) {
#pragma unroll
      for (int nb = 0; nb < 4; ++nb) {
        bf16x8 wof = *(const bf16x8*)(Wot + (size_t)(nb * 32 + l31) * 4096 + hw * 128 + ks * 16 + hi * 8);
        acc2[nb] = __builtin_amdgcn_mfma_f32_32x32x16_bf16(wof, ofrag[ks], acc2[nb], 0, 0, 0);
      }
    }
    __syncthreads();  // Ph reads done block-wide before overwrite
#pragma unroll
    for (int nb = 0; nb < 4; ++nb)
#pragma unroll
      for (int j = 0; j < 16; ++j) {
        int no = nb * 32 + (j & 3) + 8 * (j >> 2) + 4 * hi;
        Ph[l31 * 130 + no] = acc2[nb][j];  // [32][130] f32 within the slab
      }
  } else {
    __syncthreads();
  }
  __syncthreads();
  {
    float* dst = part + (size_t)g * 262144 + (size_t)qi0 * 128;
#pragma unroll
    for (int i = 0; i < 8; ++i) {
      int idx = i * 512 + tid;  // idx = q*128 + no
      int q = idx >> 7, no = idx & 127;
      int o = q * 130 + no;
      dst[idx] = smemF[o] + smemF[4224 + o] + smemF[8448 + o] + smemF[12672 + o];
    }
  }
#undef STAGE
}

extern "C" void kernel_launch(void* const* d_in, const int* in_sizes, int n_in,
                              void* d_out, int out_size, void* d_ws, size_t ws_size,
                              hipStream_t stream) {
  const float* query  = (const float*)d_in[0];
  const float* keys   = (const float*)d_in[1];
  const float* values = (const float*)d_in[2];
  const float* Wq = (const float*)d_in[3];
  const float* bq = (const float*)d_in[4];
  const float* Wk = (const float*)d_in[5];
  const float* bk = (const float*)d_in[6];
  const float* Wv = (const float*)d_in[7];
  const float* bv = (const float*)d_in[8];
  const float* Wo = (const float*)d_in[9];
  const float* bo = (const float*)d_in[10];
  float* out = (float*)d_out;
  char* ws = (char*)d_ws;
  const size_t MB = 1024 * 1024;
  const size_t NEED_MIN = 18 * MB + 512 * 1024;   // 10.5 + part 8
  const size_t NEED_BIG = 34 * MB + 512 * 1024;   // 10.5 + qproj 16 + part 8
  if (ws_size < NEED_MIN) {  // sentinel: absmax 12345 => ws too small
    ws_marker<<<1024, 256, 0, stream>>>(out);
    return;
  }
  int big = ws_size >= NEED_BIG;
  unsigned short* Wq2   = (unsigned short*)(ws);                        // 1 MiB
  unsigned short* Wkt   = (unsigned short*)(ws + 1 * MB);               // 256 KiB
  unsigned short* Wvt   = (unsigned short*)(ws + 1 * MB + 256 * 1024);  // 256 KiB
  unsigned short* Wot   = (unsigned short*)(ws + 1 * MB + 512 * 1024);  // 1 MiB
  unsigned short* kproj = (unsigned short*)(ws + 2 * MB + 512 * 1024);  // 4 MiB
  unsigned short* vt    = (unsigned short*)(ws + 6 * MB + 512 * 1024);  // 4 MiB -> 10.5
  unsigned short* qproj = (unsigned short*)(ws + 10 * MB + 512 * 1024); // 16 MiB (big)
  float* part = big ? (float*)(ws + 26 * MB + 512 * 1024)
                    : (float*)(ws + 10 * MB + 512 * 1024);              // 8 MiB

  prep_weights<<<320, 256, 0, stream>>>(Wk, Wv, Wo, Wq, Wkt, Wvt, Wot, Wq2, big);
  proj_kv<<<dim3(16, 32), 256, 0, stream>>>(keys, values, Wkt, Wvt, bk, bv, kproj, vt);

  if (big) {
    proj_q<<<dim3(64, 32), 256, 0, stream>>>(query, Wq2, bq, qproj);
    attn_kernel<0><<<512, 512, 0, stream>>>(query, Wq2, bq, qproj, kproj, vt, Wot, part);
  } else {
    attn_kernel<1><<<512, 512, 0, stream>>>(query, Wq2, bq, nullptr, kproj, vt, Wot, part);
  }
  reduce_out<<<1024, 256, 0, stream>>>(part, bo, out);
}

// Round 16
// 169.421 us; speedup vs baseline: 1.2399x; 1.2399x over previous
//
#include <hip/hip_runtime.h>
#include <math.h>

// GQA B=1 S=2048 D=128 H=32 KVH=8. d_out f32.
// Round 16: CONSOLIDATION. r11's attn kernel verbatim (best measured: 119.9us;
// every later structure regressed) + r12's LDS-tile prep_weights (coalesced
// transposes, 384 blocks) + r11's proj_all (K/V/Q one kernel). 3 dispatches.
// ws>=34.5MB confirmed in r15 -> big path (MFMA Q-proj) active.

#define SCALE 0.08838834764831843f      // 1/sqrt(128)
#define L2_10K_64 0.20762050593045952f  // log2(10000)/64

typedef short bf16x8 __attribute__((ext_vector_type(8)));
typedef float f32x4 __attribute__((ext_vector_type(4)));

__device__ __forceinline__ unsigned short f2b(float f) {
  union { float f; unsigned u; } x; x.f = f;
  return (unsigned short)((x.u + 0x7FFFu + ((x.u >> 16) & 1u)) >> 16);
}
__device__ __forceinline__ float b2f(unsigned short b) {
  union { unsigned u; float f; } x; x.u = ((unsigned)b) << 16;
  return x.f;
}
__device__ __forceinline__ void lds_dma16(void* lds, const void* g) {
  __builtin_amdgcn_global_load_lds(
      (const __attribute__((address_space(1))) unsigned int*)g,
      (__attribute__((address_space(3))) unsigned int*)lds, 16, 0, 0);
}

// ---- weight prep: LDS 64x64 tile transposes, coalesced read+write (r12) ----
// blocks: [0,32) Wk->Wkt | [32,64) Wv->Wvt | [64,192) Wo->Wot |
//         [192,320) Wq (big: transpose, small: cast) | [320,384) out=bias
__global__ __launch_bounds__(256) void prep_weights(
    const float* __restrict__ Wk, const float* __restrict__ Wv,
    const float* __restrict__ Wo, const float* __restrict__ Wq,
    const float* __restrict__ bo,
    unsigned short* __restrict__ Wkt, unsigned short* __restrict__ Wvt,
    unsigned short* __restrict__ Wot, unsigned short* __restrict__ Wq2,
    float* __restrict__ out, int big) {
  __shared__ unsigned short T[64][66];
  int b = blockIdx.x, tid = threadIdx.x;
  const float* W;
  unsigned short* D;
  int K, N, tk, tn;
  if (b < 32) {
    W = Wk; D = Wkt; K = 128; N = 1024; int ti = b;       tk = ti & 1;  tn = ti >> 1;
  } else if (b < 64) {
    W = Wv; D = Wvt; K = 128; N = 1024; int ti = b - 32;  tk = ti & 1;  tn = ti >> 1;
  } else if (b < 192) {
    W = Wo; D = Wot; K = 4096; N = 128; int ti = b - 64;  tk = ti >> 1; tn = ti & 1;
  } else if (b < 320) {
    if (!big) {
      int i0 = ((b - 192) * 256 + tid) * 16;
#pragma unroll
      for (int j = 0; j < 16; ++j) Wq2[i0 + j] = f2b(Wq[i0 + j]);
      return;
    }
    W = Wq; D = Wq2; K = 128; N = 4096; int ti = b - 192; tk = ti & 1;  tn = ti >> 1;
  } else {
    int i0 = ((b - 320) * 256 + tid) * 16;  // out = bias (attn accumulates atomically)
#pragma unroll
    for (int j = 0; j < 16; ++j) out[i0 + j] = bo[(i0 + j) & 127];
    return;
  }
  int k0 = tk * 64, n0 = tn * 64;
  int c = tid & 63, q = tid >> 6;
#pragma unroll
  for (int i = 0; i < 16; ++i) {
    int r = i * 4 + q;
    T[r][c] = f2b(W[(size_t)(k0 + r) * N + n0 + c]);  // coalesced read
  }
  __syncthreads();
#pragma unroll
  for (int i = 0; i < 16; ++i) {
    int r = i * 4 + q;
    D[(size_t)(n0 + r) * K + k0 + c] = T[c][r];  // column LDS read (2-way, free), coalesced write
  }
}

// ---- all projections (r11). bx<8: K (fused RoPE, kp flat=(g,t,d)). [8,16): V
// (fused RoPE, vt[g][d][t], view-scramble honored). bx>=16 (big): Q de-scrambled
// (H,S,D): C[mi][n] == q[h=mi>>6][s=((mi&63)<<5)|(n>>7)][d=n&127]
__global__ __launch_bounds__(256) void proj_all(
    const float* __restrict__ keys, const float* __restrict__ values,
    const float* __restrict__ query,
    const unsigned short* __restrict__ Wkt, const unsigned short* __restrict__ Wvt,
    const unsigned short* __restrict__ Wqt,
    const float* __restrict__ bk, const float* __restrict__ bv, const float* __restrict__ bq,
    unsigned short* __restrict__ kp, unsigned short* __restrict__ vt,
    unsigned short* __restrict__ qp) {
  int bx = blockIdx.x, m0 = blockIdx.y * 64;
  int tid = threadIdx.x;
  int w = tid >> 6, l = tid & 63;
  int l16 = l & 15, g4 = l >> 4;
  int arow = m0 + w * 16 + l16;
  const f32x4 fz = {0.f, 0.f, 0.f, 0.f};

  if (bx >= 16) {  // Q-mode: BN=64
    int n0 = (bx - 16) * 64;
    f32x4 acc[4];
#pragma unroll
    for (int nb = 0; nb < 4; ++nb) acc[nb] = fz;
#pragma unroll
    for (int kc = 0; kc < 4; ++kc) {
      int kbase = kc * 32 + g4 * 8;
      const float* xp = query + (size_t)arow * 128 + kbase;
      bf16x8 a;
#pragma unroll
      for (int j = 0; j < 8; ++j) a[j] = (short)f2b(xp[j]);
#pragma unroll
      for (int nb = 0; nb < 4; ++nb) {
        bf16x8 b = *(const bf16x8*)(Wqt + (size_t)(n0 + nb * 16 + l16) * 128 + kbase);
        acc[nb] = __builtin_amdgcn_mfma_f32_16x16x32_bf16(a, b, acc[nb], 0, 0, 0);
      }
    }
#pragma unroll
    for (int nb = 0; nb < 4; ++nb) {
      int n = n0 + nb * 16 + l16;
      float bvv = bq[n];
#pragma unroll
      for (int r = 0; r < 4; ++r) {
        int mi = m0 + w * 16 + g4 * 4 + r;
        int h = mi >> 6;
        int s = ((mi & 63) << 5) | (n >> 7);
        qp[((size_t)h * 2048 + s) * 128 + (n & 127)] = f2b(acc[nb][r] + bvv);
      }
    }
    return;
  }

  int vmode = bx >> 3;
  int n0 = (bx & 7) * 128, tb = bx & 7;
  const float* X = vmode ? values : keys;
  const unsigned short* Wt = vmode ? Wvt : Wkt;
  const float* bias = vmode ? bv : bk;
  f32x4 acc[8];
#pragma unroll
  for (int nb = 0; nb < 8; ++nb) acc[nb] = fz;
#pragma unroll
  for (int kc = 0; kc < 4; ++kc) {
    int kbase = kc * 32 + g4 * 8;
    const float* xp = X + (size_t)arow * 128 + kbase;
    bf16x8 a;
#pragma unroll
    for (int j = 0; j < 8; ++j) a[j] = (short)f2b(xp[j]);
#pragma unroll
    for (int nb = 0; nb < 8; ++nb) {
      bf16x8 b = *(const bf16x8*)(Wt + (size_t)(n0 + nb * 16 + l16) * 128 + kbase);
      acc[nb] = __builtin_amdgcn_mfma_f32_16x16x32_bf16(a, b, acc[nb], 0, 0, 0);
    }
  }
#pragma unroll
  for (int nb = 0; nb < 4; ++nb) {
    int d2 = nb * 16 + l16;
    float invf = exp2f(-(float)d2 * L2_10K_64);
    float blo = bias[n0 + d2], bhi = bias[n0 + d2 + 64];
#pragma unroll
    for (int r = 0; r < 4; ++r) {
      int mi = m0 + w * 16 + g4 * 4 + r;
      int t = (mi & 255) * 8 + tb;
      float ang = (float)t * invf;
      float sf, cf;
      __sincosf(ang, &sf, &cf);
      float x1 = acc[nb][r] + blo;
      float x2 = acc[nb + 4][r] + bhi;
      unsigned short lo = f2b(x1 * cf - x2 * sf);
      unsigned short hi = f2b(x2 * cf + x1 * sf);
      int g = mi >> 8;
      if (vmode) {
        vt[(size_t)g * 262144 + (size_t)d2 * 2048 + t] = lo;
        vt[(size_t)g * 262144 + (size_t)(d2 + 64) * 2048 + t] = hi;
      } else {
        kp[(size_t)g * 262144 + (size_t)t * 128 + d2] = lo;
        kp[(size_t)g * 262144 + (size_t)t * 128 + d2 + 64] = hi;
      }
    }
  }
}

__global__ void ws_marker(float* __restrict__ out) {
  out[blockIdx.x * 256 + threadIdx.x] = 12345.0f;
}

// ---- attn (r11 VERBATIM): QBLK=128, 4 waves x 32 q-rows, KVBLK=32, 2 blk/CU ----
// LDS (bytes): K[2][32][128]sh @0 (XOR chunk swizzle) | V[2][128][32]sh @16384 |
//              Ps 4 waves x [32][40]sh @32768 (10240)   total 43008
template <int FUSED_Q>
__global__ __launch_bounds__(256, 2) void attn_kernel(
    const float* __restrict__ X, const unsigned short* __restrict__ Wqb,
    const float* __restrict__ bq, const unsigned short* __restrict__ qp,
    const unsigned short* __restrict__ kp, const unsigned short* __restrict__ vt,
    const unsigned short* __restrict__ Wot, float* __restrict__ out) {
  __shared__ __align__(16) char smem[43008];
  int bid = blockIdx.x;
  int h = bid & 31, g = h & 7;
  int qi0 = (bid >> 5) * 128;
  int tid = threadIdx.x;
  int w = tid >> 6, l = tid & 63;
  int l16 = l & 15, g4 = l >> 4;

  const f32x4 fz = {0.f, 0.f, 0.f, 0.f};
  bf16x8 qfrag[2][4];

  if (FUSED_Q) {
    unsigned short* Uni = (unsigned short*)smem;  // [4][4096] shorts = 32KB
    int r0 = h * 64 + (qi0 >> 5);
    int col0 = tid * 16;
#pragma unroll
    for (int jp = 0; jp < 2; ++jp) {
      float acc[2][16];
#pragma unroll
      for (int j = 0; j < 2; ++j)
#pragma unroll
        for (int cc = 0; cc < 16; ++cc) acc[j][cc] = bq[col0 + cc];
      const float* xr0 = X + (size_t)(r0 + jp * 2) * 128;
      const float* xr1 = xr0 + 128;
      for (int k = 0; k < 128; ++k) {
        float x0 = xr0[k], x1 = xr1[k];
        bf16x8 w0 = *(const bf16x8*)(Wqb + (size_t)k * 4096 + col0);
        bf16x8 w1 = *(const bf16x8*)(Wqb + (size_t)k * 4096 + col0 + 8);
#pragma unroll
        for (int e = 0; e < 8; ++e) {
          float f0 = b2f((unsigned short)w0[e]), f1 = b2f((unsigned short)w1[e]);
          acc[0][e] += x0 * f0; acc[0][8 + e] += x0 * f1;
          acc[1][e] += x1 * f0; acc[1][8 + e] += x1 * f1;
        }
      }
#pragma unroll
      for (int j = 0; j < 2; ++j)
#pragma unroll
        for (int cc = 0; cc < 16; ++cc)
          Uni[(jp * 2 + j) * 4096 + col0 + cc] = f2b(acc[j][cc]);
    }
    __syncthreads();
#pragma unroll
    for (int a = 0; a < 2; ++a) {
      int srow = w * 32 + a * 16 + l16;
      int sj = srow >> 5, scol = (srow & 31) * 128;
#pragma unroll
      for (int kc = 0; kc < 4; ++kc)
        qfrag[a][kc] = *(const bf16x8*)&Uni[sj * 4096 + scol + kc * 32 + g4 * 8];
    }
    __syncthreads();
  } else {
#pragma unroll
    for (int a = 0; a < 2; ++a) {
      const unsigned short* qrow =
          qp + ((size_t)h * 2048 + qi0 + w * 32 + a * 16 + l16) * 128;
#pragma unroll
      for (int kc = 0; kc < 4; ++kc)
        qfrag[a][kc] = *(const bf16x8*)(qrow + kc * 32 + g4 * 8);
    }
  }

  const char* kg = (const char*)(kp + (size_t)g * 262144);
  const char* vg = (const char*)(vt + (size_t)g * 262144);
  unsigned short* PsW = (unsigned short*)(smem + 32768) + w * 1280;  // [32][40]

#define STAGE_K(tn, kb)                                                          \
  {                                                                              \
    _Pragma("unroll") for (int i = 0; i < 2; ++i) {                              \
      int off = w * 2048 + i * 1024 + l * 16;                                    \
      int row = off >> 8, ch = (off >> 4) & 15;                                  \
      int rch = ch ^ (row & 7);                                                  \
      lds_dma16(smem + (kb) * 8192 + w * 2048 + i * 1024,                        \
                kg + (size_t)(tn) * 8192 + (size_t)row * 256 + rch * 16);        \
    }                                                                            \
  }
#define STAGE_V(tn, vb)                                                          \
  {                                                                              \
    _Pragma("unroll") for (int i = 0; i < 2; ++i) {                              \
      int off = w * 2048 + i * 1024 + l * 16;                                    \
      int vrow = off >> 6, vcb = off & 63;                                       \
      lds_dma16(smem + 16384 + (vb) * 8192 + w * 2048 + i * 1024,                \
                vg + (size_t)vrow * 4096 + (size_t)(tn) * 64 + vcb);             \
    }                                                                            \
  }

  STAGE_K(0, 0);
  STAGE_V(0, 0);
  __syncthreads();

  f32x4 oacc[2][8];
#pragma unroll
  for (int a = 0; a < 2; ++a)
#pragma unroll
    for (int db = 0; db < 8; ++db) oacc[a][db] = fz;
  float lacc[2][4] = {{0.f, 0.f, 0.f, 0.f}, {0.f, 0.f, 0.f, 0.f}};

  int c = 0;
  for (int t = 0; t < 64; ++t) {
    if (t < 63) {
      STAGE_K(t + 1, c ^ 1);
      STAGE_V(t + 1, c ^ 1);
    }

    f32x4 sacc[2][2];
    sacc[0][0] = fz; sacc[0][1] = fz; sacc[1][0] = fz; sacc[1][1] = fz;
    __builtin_amdgcn_s_setprio(1);
#pragma unroll
    for (int kc = 0; kc < 4; ++kc) {
#pragma unroll
      for (int jb = 0; jb < 2; ++jb) {
        int krow = jb * 16 + l16;
        int rch = (kc * 4 + g4) ^ (krow & 7);
        bf16x8 bfrag = *(const bf16x8*)(smem + c * 8192 + krow * 256 + rch * 16);
        sacc[0][jb] = __builtin_amdgcn_mfma_f32_16x16x32_bf16(qfrag[0][kc], bfrag, sacc[0][jb], 0, 0, 0);
        sacc[1][jb] = __builtin_amdgcn_mfma_f32_16x16x32_bf16(qfrag[1][kc], bfrag, sacc[1][jb], 0, 0, 0);
      }
    }
    __builtin_amdgcn_s_setprio(0);
#pragma unroll
    for (int a = 0; a < 2; ++a) {
#pragma unroll
      for (int r = 0; r < 4; ++r) {
        unsigned short u0 = f2b(__expf(sacc[a][0][r] * SCALE));
        unsigned short u1 = f2b(__expf(sacc[a][1][r] * SCALE));
        lacc[a][r] += b2f(u0) + b2f(u1);
        PsW[(a * 16 + g4 * 4 + r) * 40 + l16] = u0;
        PsW[(a * 16 + g4 * 4 + r) * 40 + 16 + l16] = u1;
      }
    }
    bf16x8 pfrag0 = *(const bf16x8*)(PsW + (l16)*40 + g4 * 8);
    bf16x8 pfrag1 = *(const bf16x8*)(PsW + (16 + l16) * 40 + g4 * 8);
    __builtin_amdgcn_s_setprio(1);
#pragma unroll
    for (int db = 0; db < 8; ++db) {
      bf16x8 vfrag = *(const bf16x8*)(smem + 16384 + c * 8192 + (db * 16 + l16) * 64 + g4 * 16);
      oacc[0][db] = __builtin_amdgcn_mfma_f32_16x16x32_bf16(pfrag0, vfrag, oacc[0][db], 0, 0, 0);
      oacc[1][db] = __builtin_amdgcn_mfma_f32_16x16x32_bf16(pfrag1, vfrag, oacc[1][db], 0, 0, 0);
    }
    __builtin_amdgcn_s_setprio(0);
    __syncthreads();
    c ^= 1;
  }

  float invl[2][4];
#pragma unroll
  for (int a = 0; a < 2; ++a)
#pragma unroll
    for (int r = 0; r < 4; ++r) {
      float v = lacc[a][r];
#pragma unroll
      for (int off = 1; off < 16; off <<= 1) v += __shfl_xor(v, off, 64);
      invl[a][r] = 1.f / v;
    }

  unsigned short* Otile = (unsigned short*)smem;
#pragma unroll
  for (int a = 0; a < 2; ++a)
#pragma unroll
    for (int db = 0; db < 8; ++db)
#pragma unroll
      for (int r = 0; r < 4; ++r)
        Otile[(w * 32 + a * 16 + g4 * 4 + r) * 136 + db * 16 + l16] =
            f2b(oacc[a][db][r] * invl[a][r]);
  __syncthreads();
  bf16x8 a2[2][4];
#pragma unroll
  for (int a = 0; a < 2; ++a)
#pragma unroll
    for (int kc = 0; kc < 4; ++kc)
      a2[a][kc] = *(const bf16x8*)&Otile[(w * 32 + a * 16 + l16) * 136 + kc * 32 + g4 * 8];
  f32x4 acc2[2][8];
#pragma unroll
  for (int a = 0; a < 2; ++a)
#pragma unroll
    for (int nb = 0; nb < 8; ++nb) acc2[a][nb] = fz;
#pragma unroll
  for (int kc = 0; kc < 4; ++kc) {
#pragma unroll
    for (int nb = 0; nb < 8; ++nb) {
      bf16x8 b2v = *(const bf16x8*)(Wot + (size_t)(nb * 16 + l16) * 4096 + h * 128 + kc * 32 + g4 * 8);
      acc2[0][nb] = __builtin_amdgcn_mfma_f32_16x16x32_bf16(a2[0][kc], b2v, acc2[0][nb], 0, 0, 0);
      acc2[1][nb] = __builtin_amdgcn_mfma_f32_16x16x32_bf16(a2[1][kc], b2v, acc2[1][nb], 0, 0, 0);
    }
  }
#pragma unroll
  for (int a = 0; a < 2; ++a)
#pragma unroll
    for (int nb = 0; nb < 8; ++nb)
#pragma unroll
      for (int r = 0; r < 4; ++r)
        atomicAdd(&out[(size_t)(qi0 + w * 32 + a * 16 + g4 * 4 + r) * 128 + nb * 16 + l16],
                  acc2[a][nb][r]);
#undef STAGE_K
#undef STAGE_V
}

extern "C" void kernel_launch(void* const* d_in, const int* in_sizes, int n_in,
                              void* d_out, int out_size, void* d_ws, size_t ws_size,
                              hipStream_t stream) {
  const float* query  = (const float*)d_in[0];
  const float* keys   = (const float*)d_in[1];
  const float* values = (const float*)d_in[2];
  const float* Wq = (const float*)d_in[3];
  const float* bq = (const float*)d_in[4];
  const float* Wk = (const float*)d_in[5];
  const float* bk = (const float*)d_in[6];
  const float* Wv = (const float*)d_in[7];
  const float* bv = (const float*)d_in[8];
  const float* Wo = (const float*)d_in[9];
  const float* bo = (const float*)d_in[10];
  float* out = (float*)d_out;
  char* ws = (char*)d_ws;
  const size_t MB = 1024 * 1024;
  if (ws_size < 10 * MB + 512 * 1024) {  // sentinel: absmax 12345 => ws too small
    ws_marker<<<1024, 256, 0, stream>>>(out);
    return;
  }
  unsigned short* Wq2   = (unsigned short*)(ws);                        // 1 MiB
  unsigned short* Wkt   = (unsigned short*)(ws + 1 * MB);               // 256 KiB
  unsigned short* Wvt   = (unsigned short*)(ws + 1 * MB + 256 * 1024);  // 256 KiB
  unsigned short* Wot   = (unsigned short*)(ws + 1 * MB + 512 * 1024);  // 1 MiB
  unsigned short* kproj = (unsigned short*)(ws + 2 * MB + 512 * 1024);  // 4 MiB
  unsigned short* vt    = (unsigned short*)(ws + 6 * MB + 512 * 1024);  // 4 MiB -> 10.5
  unsigned short* qproj = (unsigned short*)(ws + 10 * MB + 512 * 1024); // 16 MiB (big)
  int big = ws_size >= 27 * MB;  // confirmed true on this harness (r15 FETCH evidence)

  prep_weights<<<384, 256, 0, stream>>>(Wk, Wv, Wo, Wq, bo, Wkt, Wvt, Wot, Wq2, out, big);

  if (big) {
    proj_all<<<dim3(80, 32), 256, 0, stream>>>(keys, values, query, Wkt, Wvt, Wq2,
                                               bk, bv, bq, kproj, vt, qproj);
    attn_kernel<0><<<512, 256, 0, stream>>>(query, Wq2, bq, qproj, kproj, vt, Wot, out);
  } else {
    proj_all<<<dim3(16, 32), 256, 0, stream>>>(keys, values, query, Wkt, Wvt, Wq2,
                                               bk, bv, bq, kproj, vt, qproj);
    attn_kernel<1><<<512, 256, 0, stream>>>(query, Wq2, bq, nullptr, kproj, vt, Wot, out);
  }
}

// Round 17
// 165.337 us; speedup vs baseline: 1.2705x; 1.0247x over previous
//
#include <hip/hip_runtime.h>
#include <math.h>

// GQA B=1 S=2048 D=128 H=32 KVH=8. d_out f32.
// Round 17: attn VERBATIM (r11/r16, 119us). Fix the 30us Q-projection:
// BN 64->256 (512 blocks, 4x A-reuse) + float4 X loads in all proj modes
// (was 32 scalar f32 loads/thread -> load-issue-bound, r14 vs r16 delta).

#define SCALE 0.08838834764831843f      // 1/sqrt(128)
#define L2_10K_64 0.20762050593045952f  // log2(10000)/64

typedef short bf16x8 __attribute__((ext_vector_type(8)));
typedef float f32x4 __attribute__((ext_vector_type(4)));

__device__ __forceinline__ unsigned short f2b(float f) {
  union { float f; unsigned u; } x; x.f = f;
  return (unsigned short)((x.u + 0x7FFFu + ((x.u >> 16) & 1u)) >> 16);
}
__device__ __forceinline__ float b2f(unsigned short b) {
  union { unsigned u; float f; } x; x.u = ((unsigned)b) << 16;
  return x.f;
}
__device__ __forceinline__ void lds_dma16(void* lds, const void* g) {
  __builtin_amdgcn_global_load_lds(
      (const __attribute__((address_space(1))) unsigned int*)g,
      (__attribute__((address_space(3))) unsigned int*)lds, 16, 0, 0);
}
// load 8 consecutive f32 (32B-aligned) and round to bf16x8
__device__ __forceinline__ bf16x8 ldx8(const float* p) {
  f32x4 x0 = *(const f32x4*)p;
  f32x4 x1 = *(const f32x4*)(p + 4);
  bf16x8 a;
#pragma unroll
  for (int j = 0; j < 4; ++j) a[j] = (short)f2b(x0[j]);
#pragma unroll
  for (int j = 0; j < 4; ++j) a[4 + j] = (short)f2b(x1[j]);
  return a;
}

// ---- weight prep: LDS 64x64 tile transposes, coalesced read+write ----
// blocks: [0,32) Wk->Wkt | [32,64) Wv->Wvt | [64,192) Wo->Wot |
//         [192,320) Wq (big: transpose, small: cast) | [320,384) out=bias
__global__ __launch_bounds__(256) void prep_weights(
    const float* __restrict__ Wk, const float* __restrict__ Wv,
    const float* __restrict__ Wo, const float* __restrict__ Wq,
    const float* __restrict__ bo,
    unsigned short* __restrict__ Wkt, unsigned short* __restrict__ Wvt,
    unsigned short* __restrict__ Wot, unsigned short* __restrict__ Wq2,
    float* __restrict__ out, int big) {
  __shared__ unsigned short T[64][66];
  int b = blockIdx.x, tid = threadIdx.x;
  const float* W;
  unsigned short* D;
  int K, N, tk, tn;
  if (b < 32) {
    W = Wk; D = Wkt; K = 128; N = 1024; int ti = b;       tk = ti & 1;  tn = ti >> 1;
  } else if (b < 64) {
    W = Wv; D = Wvt; K = 128; N = 1024; int ti = b - 32;  tk = ti & 1;  tn = ti >> 1;
  } else if (b < 192) {
    W = Wo; D = Wot; K = 4096; N = 128; int ti = b - 64;  tk = ti >> 1; tn = ti & 1;
  } else if (b < 320) {
    if (!big) {
      int i0 = ((b - 192) * 256 + tid) * 16;
#pragma unroll
      for (int j = 0; j < 16; ++j) Wq2[i0 + j] = f2b(Wq[i0 + j]);
      return;
    }
    W = Wq; D = Wq2; K = 128; N = 4096; int ti = b - 192; tk = ti & 1;  tn = ti >> 1;
  } else {
    int i0 = ((b - 320) * 256 + tid) * 16;  // out = bias (attn accumulates atomically)
#pragma unroll
    for (int j = 0; j < 16; ++j) out[i0 + j] = bo[(i0 + j) & 127];
    return;
  }
  int k0 = tk * 64, n0 = tn * 64;
  int c = tid & 63, q = tid >> 6;
#pragma unroll
  for (int i = 0; i < 16; ++i) {
    int r = i * 4 + q;
    T[r][c] = f2b(W[(size_t)(k0 + r) * N + n0 + c]);
  }
  __syncthreads();
#pragma unroll
  for (int i = 0; i < 16; ++i) {
    int r = i * 4 + q;
    D[(size_t)(n0 + r) * K + k0 + c] = T[c][r];
  }
}

// ---- all projections. bx<8: K (fused RoPE, kp flat=(g,t,d)). [8,16): V (fused
// RoPE, vt[g][d][t], view-scramble honored). bx>=16 (big): Q BN=256 de-scrambled
// (H,S,D): C[mi][n] == q[h=mi>>6][s=((mi&63)<<5)|(n>>7)][d=n&127]
__global__ __launch_bounds__(256) void proj_all(
    const float* __restrict__ keys, const float* __restrict__ values,
    const float* __restrict__ query,
    const unsigned short* __restrict__ Wkt, const unsigned short* __restrict__ Wvt,
    const unsigned short* __restrict__ Wqt,
    const float* __restrict__ bk, const float* __restrict__ bv, const float* __restrict__ bq,
    unsigned short* __restrict__ kp, unsigned short* __restrict__ vt,
    unsigned short* __restrict__ qp) {
  int bx = blockIdx.x, m0 = blockIdx.y * 64;
  int tid = threadIdx.x;
  int w = tid >> 6, l = tid & 63;
  int l16 = l & 15, g4 = l >> 4;
  int arow = m0 + w * 16 + l16;
  const f32x4 fz = {0.f, 0.f, 0.f, 0.f};

  if (bx >= 16) {  // ---- Q-mode: BN=256 ----
    int n0 = (bx - 16) * 256;
    f32x4 acc[16];
#pragma unroll
    for (int nb = 0; nb < 16; ++nb) acc[nb] = fz;
#pragma unroll
    for (int kc = 0; kc < 4; ++kc) {
      int kbase = kc * 32 + g4 * 8;
      bf16x8 a = ldx8(query + (size_t)arow * 128 + kbase);
#pragma unroll
      for (int nb = 0; nb < 16; ++nb) {
        bf16x8 b = *(const bf16x8*)(Wqt + (size_t)(n0 + nb * 16 + l16) * 128 + kbase);
        acc[nb] = __builtin_amdgcn_mfma_f32_16x16x32_bf16(a, b, acc[nb], 0, 0, 0);
      }
    }
#pragma unroll
    for (int nb = 0; nb < 16; ++nb) {
      int n = n0 + nb * 16 + l16;
      float bvv = bq[n];
#pragma unroll
      for (int r = 0; r < 4; ++r) {
        int mi = m0 + w * 16 + g4 * 4 + r;
        int h = mi >> 6;
        int s = ((mi & 63) << 5) | (n >> 7);
        qp[((size_t)h * 2048 + s) * 128 + (n & 127)] = f2b(acc[nb][r] + bvv);
      }
    }
    return;
  }

  int vmode = bx >> 3;
  int n0 = (bx & 7) * 128, tb = bx & 7;
  const float* X = vmode ? values : keys;
  const unsigned short* Wt = vmode ? Wvt : Wkt;
  const float* bias = vmode ? bv : bk;
  f32x4 acc[8];
#pragma unroll
  for (int nb = 0; nb < 8; ++nb) acc[nb] = fz;
#pragma unroll
  for (int kc = 0; kc < 4; ++kc) {
    int kbase = kc * 32 + g4 * 8;
    bf16x8 a = ldx8(X + (size_t)arow * 128 + kbase);
#pragma unroll
    for (int nb = 0; nb < 8; ++nb) {
      bf16x8 b = *(const bf16x8*)(Wt + (size_t)(n0 + nb * 16 + l16) * 128 + kbase);
      acc[nb] = __builtin_amdgcn_mfma_f32_16x16x32_bf16(a, b, acc[nb], 0, 0, 0);
    }
  }
#pragma unroll
  for (int nb = 0; nb < 4; ++nb) {
    int d2 = nb * 16 + l16;
    float invf = exp2f(-(float)d2 * L2_10K_64);
    float blo = bias[n0 + d2], bhi = bias[n0 + d2 + 64];
#pragma unroll
    for (int r = 0; r < 4; ++r) {
      int mi = m0 + w * 16 + g4 * 4 + r;
      int t = (mi & 255) * 8 + tb;
      float ang = (float)t * invf;
      float sf, cf;
      __sincosf(ang, &sf, &cf);
      float x1 = acc[nb][r] + blo;
      float x2 = acc[nb + 4][r] + bhi;
      unsigned short lo = f2b(x1 * cf - x2 * sf);
      unsigned short hi = f2b(x2 * cf + x1 * sf);
      int g = mi >> 8;
      if (vmode) {
        vt[(size_t)g * 262144 + (size_t)d2 * 2048 + t] = lo;
        vt[(size_t)g * 262144 + (size_t)(d2 + 64) * 2048 + t] = hi;
      } else {
        kp[(size_t)g * 262144 + (size_t)t * 128 + d2] = lo;
        kp[(size_t)g * 262144 + (size_t)t * 128 + d2 + 64] = hi;
      }
    }
  }
}

__global__ void ws_marker(float* __restrict__ out) {
  out[blockIdx.x * 256 + threadIdx.x] = 12345.0f;
}

// ---- attn (r11/r16 VERBATIM): QBLK=128, 4 waves x 32 q-rows, KVBLK=32 ----
template <int FUSED_Q>
__global__ __launch_bounds__(256, 2) void attn_kernel(
    const float* __restrict__ X, const unsigned short* __restrict__ Wqb,
    const float* __restrict__ bq, const unsigned short* __restrict__ qp,
    const unsigned short* __restrict__ kp, const unsigned short* __restrict__ vt,
    const unsigned short* __restrict__ Wot, float* __restrict__ out) {
  __shared__ __align__(16) char smem[43008];
  int bid = blockIdx.x;
  int h = bid & 31, g = h & 7;
  int qi0 = (bid >> 5) * 128;
  int tid = threadIdx.x;
  int w = tid >> 6, l = tid & 63;
  int l16 = l & 15, g4 = l >> 4;

  const f32x4 fz = {0.f, 0.f, 0.f, 0.f};
  bf16x8 qfrag[2][4];

  if (FUSED_Q) {
    unsigned short* Uni = (unsigned short*)smem;  // [4][4096] shorts = 32KB
    int r0 = h * 64 + (qi0 >> 5);
    int col0 = tid * 16;
#pragma unroll
    for (int jp = 0; jp < 2; ++jp) {
      float acc[2][16];
#pragma unroll
      for (int j = 0; j < 2; ++j)
#pragma unroll
        for (int cc = 0; cc < 16; ++cc) acc[j][cc] = bq[col0 + cc];
      const float* xr0 = X + (size_t)(r0 + jp * 2) * 128;
      const float* xr1 = xr0 + 128;
      for (int k = 0; k < 128; ++k) {
        float x0 = xr0[k], x1 = xr1[k];
        bf16x8 w0 = *(const bf16x8*)(Wqb + (size_t)k * 4096 + col0);
        bf16x8 w1 = *(const bf16x8*)(Wqb + (size_t)k * 4096 + col0 + 8);
#pragma unroll
        for (int e = 0; e < 8; ++e) {
          float f0 = b2f((unsigned short)w0[e]), f1 = b2f((unsigned short)w1[e]);
          acc[0][e] += x0 * f0; acc[0][8 + e] += x0 * f1;
          acc[1][e] += x1 * f0; acc[1][8 + e] += x1 * f1;
        }
      }
#pragma unroll
      for (int j = 0; j < 2; ++j)
#pragma unroll
        for (int cc = 0; cc < 16; ++cc)
          Uni[(jp * 2 + j) * 4096 + col0 + cc] = f2b(acc[j][cc]);
    }
    __syncthreads();
#pragma unroll
    for (int a = 0; a < 2; ++a) {
      int srow = w * 32 + a * 16 + l16;
      int sj = srow >> 5, scol = (srow & 31) * 128;
#pragma unroll
      for (int kc = 0; kc < 4; ++kc)
        qfrag[a][kc] = *(const bf16x8*)&Uni[sj * 4096 + scol + kc * 32 + g4 * 8];
    }
    __syncthreads();
  } else {
#pragma unroll
    for (int a = 0; a < 2; ++a) {
      const unsigned short* qrow =
          qp + ((size_t)h * 2048 + qi0 + w * 32 + a * 16 + l16) * 128;
#pragma unroll
      for (int kc = 0; kc < 4; ++kc)
        qfrag[a][kc] = *(const bf16x8*)(qrow + kc * 32 + g4 * 8);
    }
  }

  const char* kg = (const char*)(kp + (size_t)g * 262144);
  const char* vg = (const char*)(vt + (size_t)g * 262144);
  unsigned short* PsW = (unsigned short*)(smem + 32768) + w * 1280;  // [32][40]

#define STAGE_K(tn, kb)                                                          \
  {                                                                              \
    _Pragma("unroll") for (int i = 0; i < 2; ++i) {                              \
      int off = w * 2048 + i * 1024 + l * 16;                                    \
      int row = off >> 8, ch = (off >> 4) & 15;                                  \
      int rch = ch ^ (row & 7);                                                  \
      lds_dma16(smem + (kb) * 8192 + w * 2048 + i * 1024,                        \
                kg + (size_t)(tn) * 8192 + (size_t)row * 256 + rch * 16);        \
    }                                                                            \
  }
#define STAGE_V(tn, vb)                                                          \
  {                                                                              \
    _Pragma("unroll") for (int i = 0; i < 2; ++i) {                              \
      int off = w * 2048 + i * 1024 + l * 16;                                    \
      int vrow = off >> 6, vcb = off & 63;                                       \
      lds_dma16(smem + 16384 + (vb) * 8192 + w * 2048 + i * 1024,                \
                vg + (size_t)vrow * 4096 + (size_t)(tn) * 64 + vcb);             \
    }                                                                            \
  }

  STAGE_K(0, 0);
  STAGE_V(0, 0);
  __syncthreads();

  f32x4 oacc[2][8];
#pragma unroll
  for (int a = 0; a < 2; ++a)
#pragma unroll
    for (int db = 0; db < 8; ++db) oacc[a][db] = fz;
  float lacc[2][4] = {{0.f, 0.f, 0.f, 0.f}, {0.f, 0.f, 0.f, 0.f}};

  int c = 0;
  for (int t = 0; t < 64; ++t) {
    if (t < 63) {
      STAGE_K(t + 1, c ^ 1);
      STAGE_V(t + 1, c ^ 1);
    }

    f32x4 sacc[2][2];
    sacc[0][0] = fz; sacc[0][1] = fz; sacc[1][0] = fz; sacc[1][1] = fz;
    __builtin_amdgcn_s_setprio(1);
#pragma unroll
    for (int kc = 0; kc < 4; ++kc) {
#pragma unroll
      for (int jb = 0; jb < 2; ++jb) {
        int krow = jb * 16 + l16;
        int rch = (kc * 4 + g4) ^ (krow & 7);
        bf16x8 bfrag = *(const bf16x8*)(smem + c * 8192 + krow * 256 + rch * 16);
        sacc[0][jb] = __builtin_amdgcn_mfma_f32_16x16x32_bf16(qfrag[0][kc], bfrag, sacc[0][jb], 0, 0, 0);
        sacc[1][jb] = __builtin_amdgcn_mfma_f32_16x16x32_bf16(qfrag[1][kc], bfrag, sacc[1][jb], 0, 0, 0);
      }
    }
    __builtin_amdgcn_s_setprio(0);
#pragma unroll
    for (int a = 0; a < 2; ++a) {
#pragma unroll
      for (int r = 0; r < 4; ++r) {
        unsigned short u0 = f2b(__expf(sacc[a][0][r] * SCALE));
        unsigned short u1 = f2b(__expf(sacc[a][1][r] * SCALE));
        lacc[a][r] += b2f(u0) + b2f(u1);
        PsW[(a * 16 + g4 * 4 + r) * 40 + l16] = u0;
        PsW[(a * 16 + g4 * 4 + r) * 40 + 16 + l16] = u1;
      }
    }
    bf16x8 pfrag0 = *(const bf16x8*)(PsW + (l16)*40 + g4 * 8);
    bf16x8 pfrag1 = *(const bf16x8*)(PsW + (16 + l16) * 40 + g4 * 8);
    __builtin_amdgcn_s_setprio(1);
#pragma unroll
    for (int db = 0; db < 8; ++db) {
      bf16x8 vfrag = *(const bf16x8*)(smem + 16384 + c * 8192 + (db * 16 + l16) * 64 + g4 * 16);
      oacc[0][db] = __builtin_amdgcn_mfma_f32_16x16x32_bf16(pfrag0, vfrag, oacc[0][db], 0, 0, 0);
      oacc[1][db] = __builtin_amdgcn_mfma_f32_16x16x32_bf16(pfrag1, vfrag, oacc[1][db], 0, 0, 0);
    }
    __builtin_amdgcn_s_setprio(0);
    __syncthreads();
    c ^= 1;
  }

  float invl[2][4];
#pragma unroll
  for (int a = 0; a < 2; ++a)
#pragma unroll
    for (int r = 0; r < 4; ++r) {
      float v = lacc[a][r];
#pragma unroll
      for (int off = 1; off < 16; off <<= 1) v += __shfl_xor(v, off, 64);
      invl[a][r] = 1.f / v;
    }

  unsigned short* Otile = (unsigned short*)smem;
#pragma unroll
  for (int a = 0; a < 2; ++a)
#pragma unroll
    for (int db = 0; db < 8; ++db)
#pragma unroll
      for (int r = 0; r < 4; ++r)
        Otile[(w * 32 + a * 16 + g4 * 4 + r) * 136 + db * 16 + l16] =
            f2b(oacc[a][db][r] * invl[a][r]);
  __syncthreads();
  bf16x8 a2[2][4];
#pragma unroll
  for (int a = 0; a < 2; ++a)
#pragma unroll
    for (int kc = 0; kc < 4; ++kc)
      a2[a][kc] = *(const bf16x8*)&Otile[(w * 32 + a * 16 + l16) * 136 + kc * 32 + g4 * 8];
  f32x4 acc2[2][8];
#pragma unroll
  for (int a = 0; a < 2; ++a)
#pragma unroll
    for (int nb = 0; nb < 8; ++nb) acc2[a][nb] = fz;
#pragma unroll
  for (int kc = 0; kc < 4; ++kc) {
#pragma unroll
    for (int nb = 0; nb < 8; ++nb) {
      bf16x8 b2v = *(const bf16x8*)(Wot + (size_t)(nb * 16 + l16) * 4096 + h * 128 + kc * 32 + g4 * 8);
      acc2[0][nb] = __builtin_amdgcn_mfma_f32_16x16x32_bf16(a2[0][kc], b2v, acc2[0][nb], 0, 0, 0);
      acc2[1][nb] = __builtin_amdgcn_mfma_f32_16x16x32_bf16(a2[1][kc], b2v, acc2[1][nb], 0, 0, 0);
    }
  }
#pragma unroll
  for (int a = 0; a < 2; ++a)
#pragma unroll
    for (int nb = 0; nb < 8; ++nb)
#pragma unroll
      for (int r = 0; r < 4; ++r)
        atomicAdd(&out[(size_t)(qi0 + w * 32 + a * 16 + g4 * 4 + r) * 128 + nb * 16 + l16],
                  acc2[a][nb][r]);
#undef STAGE_K
#undef STAGE_V
}

extern "C" void kernel_launch(void* const* d_in, const int* in_sizes, int n_in,
                              void* d_out, int out_size, void* d_ws, size_t ws_size,
                              hipStream_t stream) {
  const float* query  = (const float*)d_in[0];
  const float* keys   = (const float*)d_in[1];
  const float* values = (const float*)d_in[2];
  const float* Wq = (const float*)d_in[3];
  const float* bq = (const float*)d_in[4];
  const float* Wk = (const float*)d_in[5];
  const float* bk = (const float*)d_in[6];
  const float* Wv = (const float*)d_in[7];
  const float* bv = (const float*)d_in[8];
  const float* Wo = (const float*)d_in[9];
  const float* bo = (const float*)d_in[10];
  float* out = (float*)d_out;
  char* ws = (char*)d_ws;
  const size_t MB = 1024 * 1024;
  if (ws_size < 10 * MB + 512 * 1024) {  // sentinel: absmax 12345 => ws too small
    ws_marker<<<1024, 256, 0, stream>>>(out);
    return;
  }
  unsigned short* Wq2   = (unsigned short*)(ws);                        // 1 MiB
  unsigned short* Wkt   = (unsigned short*)(ws + 1 * MB);               // 256 KiB
  unsigned short* Wvt   = (unsigned short*)(ws + 1 * MB + 256 * 1024);  // 256 KiB
  unsigned short* Wot   = (unsigned short*)(ws + 1 * MB + 512 * 1024);  // 1 MiB
  unsigned short* kproj = (unsigned short*)(ws + 2 * MB + 512 * 1024);  // 4 MiB
  unsigned short* vt    = (unsigned short*)(ws + 6 * MB + 512 * 1024);  // 4 MiB -> 10.5
  unsigned short* qproj = (unsigned short*)(ws + 10 * MB + 512 * 1024); // 16 MiB (big)
  int big = ws_size >= 27 * MB;

  prep_weights<<<384, 256, 0, stream>>>(Wk, Wv, Wo, Wq, bo, Wkt, Wvt, Wot, Wq2, out, big);

  if (big) {
    proj_all<<<dim3(32, 32), 256, 0, stream>>>(keys, values, query, Wkt, Wvt, Wq2,
                                               bk, bv, bq, kproj, vt, qproj);
    attn_kernel<0><<<512, 256, 0, stream>>>(query, Wq2, bq, qproj, kproj, vt, Wot, out);
  } else {
    proj_all<<<dim3(16, 32), 256, 0, stream>>>(keys, values, query, Wkt, Wvt, Wq2,
                                               bk, bv, bq, kproj, vt, qproj);
    attn_kernel<1><<<512, 256, 0, stream>>>(query, Wq2, bq, nullptr, kproj, vt, Wot, out);
  }
}